// Round 9
// baseline (213.571 us; speedup 1.0000x reference)
//
#include <hip/hip_runtime.h>

#define B 8
#define N 2048
#define D 64
#define BN (B*N)
#define CAP 64
#define NWH 128        // u16 half-words per column (128*16 = 2048 rows)

// ---- A: full-residency scan + proj.  1024 blocks x 512 threads (exactly
// 2048 thr/CU on 256 CUs).  Block = (b, w): 2048 cols x 16 rows scan unit,
// then 16 rows of proj.  No dependency between the two parts.
__global__ __launch_bounds__(512, 8) void kA_scan_proj(
        const float* __restrict__ adj, unsigned short* __restrict__ masks,
        const float* __restrict__ x, const float* __restrict__ U0,
        const float* __restrict__ b0, float* __restrict__ h0) {
    __shared__ float Uld[D * D];
    __shared__ float bld[D];
    const int tid = threadIdx.x;
    const int bid = blockIdx.x;

    // scan: batch b = bid>>7, half-word w = bid&127, cols tid*4..+3
    {
        int b = bid >> 7;
        int w = bid & 127;
        int i0 = tid * 4;
        const float* base = adj + (size_t)b * N * N + (size_t)(w * 16) * N + i0;
        unsigned m0 = 0, m1 = 0, m2 = 0, m3 = 0;
#pragma unroll 8
        for (int jj = 0; jj < 16; ++jj) {      // 8 float4 loads in flight
            float4 v = *(const float4*)(base + (size_t)jj * N);
            m0 |= (v.x != 0.f ? 1u : 0u) << jj;
            m1 |= (v.y != 0.f ? 1u : 0u) << jj;
            m2 |= (v.z != 0.f ? 1u : 0u) << jj;
            m3 |= (v.w != 0.f ? 1u : 0u) << jj;
        }
        ushort4 mm = make_ushort4((unsigned short)m0, (unsigned short)m1,
                                  (unsigned short)m2, (unsigned short)m3);
        *(ushort4*)(masks + (size_t)w * BN + b * N + i0) = mm;
    }

    // proj: rows bid*16 .. +15, 2 rows per wave
    {
#pragma unroll
        for (int q = 0; q < 8; ++q) Uld[tid + q * 512] = U0[tid + q * 512];
        if (tid < D) bld[tid] = b0[tid];
        __syncthreads();
        int wid = tid >> 6, lane = tid & 63;
#pragma unroll
        for (int rr = 0; rr < 2; ++rr) {
            int r = bid * 16 + wid * 2 + rr;
            float xv = x[(size_t)r * D + lane];
            float o0 = bld[lane], o1 = 0.f, o2 = 0.f, o3 = 0.f;
#pragma unroll
            for (int k = 0; k < D; k += 4) {
                o0 = fmaf(__shfl(xv, k),     Uld[(k)     * D + lane], o0);
                o1 = fmaf(__shfl(xv, k + 1), Uld[(k + 1) * D + lane], o1);
                o2 = fmaf(__shfl(xv, k + 2), Uld[(k + 2) * D + lane], o2);
                o3 = fmaf(__shfl(xv, k + 3), Uld[(k + 3) * D + lane], o3);
            }
            h0[(size_t)r * D + lane] = (o0 + o1) + (o2 + o3);
        }
    }
}

// ---- B: u16 masks -> per-column neighbor lists ([col][CAP]) + degree ----
// 256 blocks x 64 threads: spreads over all CUs.
__global__ __launch_bounds__(64) void kB_lists(const unsigned short* __restrict__ masks,
        unsigned short* __restrict__ cols, int* __restrict__ cnt) {
    int col = blockIdx.x * 64 + threadIdx.x;
    unsigned short* cl = cols + (size_t)col * CAP;
    int p = 0;
    for (int wb = 0; wb < NWH; wb += 8) {
        unsigned mw[8];
#pragma unroll
        for (int q = 0; q < 8; ++q)            // 8 loads in flight
            mw[q] = masks[(size_t)(wb + q) * BN + col];
#pragma unroll
        for (int q = 0; q < 8; ++q) {
            unsigned m = mw[q];
            int jb = (wb + q) * 16;
            while (m) {
                int t = __builtin_ctz(m);
                m &= m - 1;
                if (p < CAP) cl[p] = (unsigned short)(jb + t);
                ++p;
            }
        }
    }
    cnt[col] = p;
}

// ---- L: one GCN layer, full residency.  1024 blocks x 512 thr, 2 rows/wave.
// If pg != nullptr, also writes pg[bid][d] = sum of this block's 16 output rows.
__global__ __launch_bounds__(512, 8) void kL_layer(const float* __restrict__ hin,
        const unsigned short* __restrict__ cols, const int* __restrict__ cnt,
        const float* __restrict__ U, float* __restrict__ hout,
        float* __restrict__ pg) {
    __shared__ float Uld[D * D];
    __shared__ float part[8][D];
    const int tid = threadIdx.x;
    const int bid = blockIdx.x;
#pragma unroll
    for (int q = 0; q < 8; ++q) Uld[tid + q * 512] = U[tid + q * 512];
    __syncthreads();
    int wid = tid >> 6, lane = tid & 63;
    float rsum = 0.f;
#pragma unroll
    for (int rr = 0; rr < 2; ++rr) {
        int r = bid * 16 + wid * 2 + rr;
        int b = r >> 11;
        int c = cnt[r];
        int kmax = c < CAP ? c : CAP;
        const float* hb = hin + ((size_t)b << 11) * D;
        const unsigned short* cl = cols + (size_t)r * CAP;
        float acc = 0.f;
        int k = 0;
        for (; k + 8 <= kmax; k += 8) {        // full batches: 8 gathers in flight
            uint4 w4 = *(const uint4*)(cl + k);
            float a0 = hb[(size_t)(w4.x & 0xffff) * D + lane];
            float a1 = hb[(size_t)(w4.x >> 16)    * D + lane];
            float a2 = hb[(size_t)(w4.y & 0xffff) * D + lane];
            float a3 = hb[(size_t)(w4.y >> 16)    * D + lane];
            float a4 = hb[(size_t)(w4.z & 0xffff) * D + lane];
            float a5 = hb[(size_t)(w4.z >> 16)    * D + lane];
            float a6 = hb[(size_t)(w4.w & 0xffff) * D + lane];
            float a7 = hb[(size_t)(w4.w >> 16)    * D + lane];
            acc += ((a0 + a1) + (a2 + a3)) + ((a4 + a5) + (a6 + a7));
        }
        if (k < kmax) {                        // predicated final batch (no serial tail)
            uint4 w4 = *(const uint4*)(cl + k);   // cols row is CAP-sized: safe
            float a0 = hb[(size_t)(w4.x & 0xffff) * D + lane];
            float a1 = hb[(size_t)(w4.x >> 16)    * D + lane];
            float a2 = hb[(size_t)(w4.y & 0xffff) * D + lane];
            float a3 = hb[(size_t)(w4.y >> 16)    * D + lane];
            float a4 = hb[(size_t)(w4.z & 0xffff) * D + lane];
            float a5 = hb[(size_t)(w4.z >> 16)    * D + lane];
            float a6 = hb[(size_t)(w4.w & 0xffff) * D + lane];
            float a7 = hb[(size_t)(w4.w >> 16)    * D + lane];
            acc += (k + 0 < kmax ? a0 : 0.f) + (k + 1 < kmax ? a1 : 0.f)
                 + (k + 2 < kmax ? a2 : 0.f) + (k + 3 < kmax ? a3 : 0.f)
                 + (k + 4 < kmax ? a4 : 0.f) + (k + 5 < kmax ? a5 : 0.f)
                 + (k + 6 < kmax ? a6 : 0.f) + (k + 7 < kmax ? a7 : 0.f);
        }
        float o0 = 0.f, o1 = 0.f, o2 = 0.f, o3 = 0.f;
#pragma unroll
        for (int d = 0; d < D; d += 4) {       // 4 independent fma chains
            o0 = fmaf(__shfl(acc, d),     Uld[(d)     * D + lane], o0);
            o1 = fmaf(__shfl(acc, d + 1), Uld[(d + 1) * D + lane], o1);
            o2 = fmaf(__shfl(acc, d + 2), Uld[(d + 2) * D + lane], o2);
            o3 = fmaf(__shfl(acc, d + 3), Uld[(d + 3) * D + lane], o3);
        }
        float ov = (o0 + o1) + (o2 + o3);
        ov = fmaxf(ov / (float)c, 0.f);
        hout[(size_t)r * D + lane] = ov;
        rsum += ov;
    }
    if (pg != nullptr) {                       // per-block row-sum partials
        part[wid][lane] = rsum;
        __syncthreads();
        if (wid == 0) {
            float s = 0.f;
#pragma unroll
            for (int q = 0; q < 8; ++q) s += part[q][lane];
            pg[bid * D + lane] = s;
        }
    }
}

// ---- Head: 1 block x 512.  Wave w handles batch w: reduce 128 pg partials,
// then out[b] = P . relu(Q @ m[b]).
__global__ __launch_bounds__(512) void kHead(const float* __restrict__ pg,
        const float* __restrict__ Q, const float* __restrict__ P,
        float* __restrict__ out) {
    int wid = threadIdx.x >> 6, lane = threadIdx.x & 63;
    float md = 0.f;
#pragma unroll 8
    for (int k = 0; k < 128; ++k) md += pg[(wid * 128 + k) * D + lane];
    md *= (1.0f / N);                           // m[b][lane]
    float t = 0.f;
#pragma unroll 8
    for (int k = 0; k < D; ++k) t = fmaf(Q[lane * D + k], __shfl(md, k), t);
    t = fmaxf(t, 0.f);
    float v = t * P[lane];
    for (int off = 32; off; off >>= 1) v += __shfl_down(v, off);
    if (lane == 0) out[wid] = v;
}

extern "C" void kernel_launch(void* const* d_in, const int* in_sizes, int n_in,
                              void* d_out, int out_size, void* d_ws, size_t ws_size,
                              hipStream_t stream) {
    const float* x   = (const float*)d_in[0];
    const float* adj = (const float*)d_in[1];
    const float* U0  = (const float*)d_in[2];
    const float* b0  = (const float*)d_in[3];
    const float* Us  = (const float*)d_in[4];
    const float* Q   = (const float*)d_in[5];
    const float* P   = (const float*)d_in[6];
    float* out = (float*)d_out;

    char* ws = (char*)d_ws;
    size_t off = 0;
    float* h0 = (float*)(ws + off); off += (size_t)BN * D * sizeof(float);  // 4 MB
    float* h1 = (float*)(ws + off); off += (size_t)BN * D * sizeof(float);  // 4 MB
    unsigned short* cols = (unsigned short*)(ws + off);
    off += (size_t)CAP * BN * sizeof(unsigned short);                       // 2 MB
    int* cnt = (int*)(ws + off); off += (size_t)BN * sizeof(int);           // 64 KB
    float* pg = (float*)(ws + off); off += (size_t)1024 * D * sizeof(float); // 256 KB

    // masks alias h1 (exactly 4 MB): consumed by kB before layer 0 writes h1.
    unsigned short* masks = (unsigned short*)h1;

    kA_scan_proj<<<1024, 512, 0, stream>>>(adj, masks, x, U0, b0, h0);
    kB_lists<<<BN / 64, 64, 0, stream>>>(masks, cols, cnt);
    kL_layer<<<1024, 512, 0, stream>>>(h0, cols, cnt, Us + 0 * D * D, h1, nullptr);
    kL_layer<<<1024, 512, 0, stream>>>(h1, cols, cnt, Us + 1 * D * D, h0, nullptr);
    kL_layer<<<1024, 512, 0, stream>>>(h0, cols, cnt, Us + 2 * D * D, h1, pg);
    kHead<<<1, 512, 0, stream>>>(pg, Q, P, out);
}

// Round 10
// 109.240 us; speedup vs baseline: 1.9551x; 1.9551x over previous
//
#include <hip/hip_runtime.h>

#define B 8
#define N 2048
#define D 64
#define BN (B*N)
#define CAP 64

// ---- node 1: scan -> lists (+ proj), no intermediate mask buffer ----
// blocks [0,256): block = (b = bid>>5, chunk = bid&31) owns 64 columns over the
//   FULL j range. Thread t: j-octave jb=t>>5 (256 rows), col-pair cp=t&31.
//   Column bitmasks accumulate in LDS (thread-disjoint words, no atomics),
//   then 64 threads extract neighbor lists + exact degree.
// blocks [256,512): h0 = x @ U0 + b0, 16 rows/wave.
__global__ __launch_bounds__(256) void kSLP(
        const float* __restrict__ adj, const float* __restrict__ x,
        const float* __restrict__ U0, const float* __restrict__ b0,
        unsigned short* __restrict__ cols, int* __restrict__ cnt,
        float* __restrict__ h0) {
    __shared__ unsigned sh[64 * 65 + 64];      // 16.9 KB, aliased by both paths
    const int tid = threadIdx.x;
    const int bid = blockIdx.x;
    if (bid < 256) {
        unsigned (*lmask)[65] = (unsigned(*)[65])sh;   // [64 cols][64 words +pad]
        int b  = bid >> 5, ck = bid & 31;
        int jb = tid >> 5;                     // j octave: rows jb*256 .. +255
        int cp = tid & 31;                     // col pair within chunk
        int c0 = cp * 2, c1 = cp * 2 + 1;
        const float* base = adj + (size_t)b * N * N + (size_t)(jb * 256) * N
                            + ck * 64 + cp * 2;
        for (int ws = 0; ws < 8; ++ws) {       // 8 words per octave
            unsigned w0 = 0, w1 = 0;
#pragma unroll 8
            for (int i = 0; i < 32; ++i) {     // j = jb*256 + ws*32 + i
                float2 v = *(const float2*)(base + (size_t)(ws * 32 + i) * N);
                w0 |= (v.x != 0.f ? 1u : 0u) << i;
                w1 |= (v.y != 0.f ? 1u : 0u) << i;
            }
            lmask[c0][jb * 8 + ws] = w0;       // thread-disjoint words
            lmask[c1][jb * 8 + ws] = w1;
        }
        __syncthreads();
        if (tid < 64) {                        // extract lists, j ascending
            int gcol = b * N + ck * 64 + tid;
            unsigned short* cl = cols + (size_t)gcol * CAP;
            int p = 0;
            for (int w = 0; w < 64; ++w) {
                unsigned m = lmask[tid][w];
                int jbase = w * 32;
                while (m) {
                    int t = __builtin_ctz(m);
                    m &= m - 1;
                    if (p < CAP) cl[p] = (unsigned short)(jbase + t);
                    ++p;
                }
            }
            cnt[gcol] = p;                     // exact degree (adj is {0,1})
        }
    } else {
        float* Uld = (float*)sh;               // 4096 floats
        float* bld = (float*)sh + 4096;        // 64 floats (sh has 4288 words)
#pragma unroll
        for (int q = 0; q < 16; ++q) Uld[tid + q * 256] = U0[tid + q * 256];
        if (tid < D) bld[tid] = b0[tid];
        __syncthreads();
        int wid = tid >> 6, lane = tid & 63;
        int gw = (bid - 256) * 4 + wid;        // wave id [0, 1024)
        for (int rr = 0; rr < 16; ++rr) {
            int r = gw * 16 + rr;              // row [0, 16384)
            float xv = x[(size_t)r * D + lane];
            float o0 = bld[lane], o1 = 0.f, o2 = 0.f, o3 = 0.f;
#pragma unroll
            for (int k = 0; k < D; k += 4) {
                o0 = fmaf(__shfl(xv, k),     Uld[(k)     * D + lane], o0);
                o1 = fmaf(__shfl(xv, k + 1), Uld[(k + 1) * D + lane], o1);
                o2 = fmaf(__shfl(xv, k + 2), Uld[(k + 2) * D + lane], o2);
                o3 = fmaf(__shfl(xv, k + 3), Uld[(k + 3) * D + lane], o3);
            }
            h0[(size_t)r * D + lane] = (o0 + o1) + (o2 + o3);
        }
    }
}

// ---- GCN layer: 2 rows/wave, both rows' gather batches in flight (16 loads) ----
// 2048 blocks x 256 thr; block owns rows bid*8..+7 (never straddles a batch).
// If pg != nullptr also writes pg[bid][d] = sum of this block's 8 output rows.
__global__ __launch_bounds__(256) void kL(const float* __restrict__ hin,
        const unsigned short* __restrict__ cols, const int* __restrict__ cnt,
        const float* __restrict__ U, float* __restrict__ hout,
        float* __restrict__ pg) {
    __shared__ float Uld[D * D];
    __shared__ float part[4][D];
    const int tid = threadIdx.x;
    const int bid = blockIdx.x;
#pragma unroll
    for (int q = 0; q < 16; ++q) Uld[tid + q * 256] = U[tid + q * 256];
    __syncthreads();
    int wid = tid >> 6, lane = tid & 63;
    int r0 = bid * 8 + wid * 2, r1 = r0 + 1;
    const float* hb = hin + ((size_t)(r0 >> 11) << 11) * D;   // batch base
    int ca = cnt[r0], cb = cnt[r1];
    int kma = ca < CAP ? ca : CAP, kmb = cb < CAP ? cb : CAP;
    const unsigned short* la = cols + (size_t)r0 * CAP;
    const unsigned short* lb = cols + (size_t)r1 * CAP;
    float acca = 0.f, accb = 0.f;
    int km = kma > kmb ? kma : kmb;
    for (int k = 0; k < km; k += 8) {          // 16 gathers in flight
        uint4 wa = *(const uint4*)(la + k);
        uint4 wb = *(const uint4*)(lb + k);
        float a0 = hb[(size_t)(wa.x & 0xffff) * D + lane];
        float a1 = hb[(size_t)(wa.x >> 16)    * D + lane];
        float a2 = hb[(size_t)(wa.y & 0xffff) * D + lane];
        float a3 = hb[(size_t)(wa.y >> 16)    * D + lane];
        float a4 = hb[(size_t)(wa.z & 0xffff) * D + lane];
        float a5 = hb[(size_t)(wa.z >> 16)    * D + lane];
        float a6 = hb[(size_t)(wa.w & 0xffff) * D + lane];
        float a7 = hb[(size_t)(wa.w >> 16)    * D + lane];
        float b0_ = hb[(size_t)(wb.x & 0xffff) * D + lane];
        float b1_ = hb[(size_t)(wb.x >> 16)    * D + lane];
        float b2_ = hb[(size_t)(wb.y & 0xffff) * D + lane];
        float b3_ = hb[(size_t)(wb.y >> 16)    * D + lane];
        float b4_ = hb[(size_t)(wb.z & 0xffff) * D + lane];
        float b5_ = hb[(size_t)(wb.z >> 16)    * D + lane];
        float b6_ = hb[(size_t)(wb.w & 0xffff) * D + lane];
        float b7_ = hb[(size_t)(wb.w >> 16)    * D + lane];
        acca += ((k + 0 < kma ? a0 : 0.f) + (k + 1 < kma ? a1 : 0.f))
              + ((k + 2 < kma ? a2 : 0.f) + (k + 3 < kma ? a3 : 0.f))
              + ((k + 4 < kma ? a4 : 0.f) + (k + 5 < kma ? a5 : 0.f))
              + ((k + 6 < kma ? a6 : 0.f) + (k + 7 < kma ? a7 : 0.f));
        accb += ((k + 0 < kmb ? b0_ : 0.f) + (k + 1 < kmb ? b1_ : 0.f))
              + ((k + 2 < kmb ? b2_ : 0.f) + (k + 3 < kmb ? b3_ : 0.f))
              + ((k + 4 < kmb ? b4_ : 0.f) + (k + 5 < kmb ? b5_ : 0.f))
              + ((k + 6 < kmb ? b6_ : 0.f) + (k + 7 < kmb ? b7_ : 0.f));
    }
    float oa0 = 0.f, oa1 = 0.f, oa2 = 0.f, oa3 = 0.f;
    float ob0 = 0.f, ob1 = 0.f, ob2 = 0.f, ob3 = 0.f;
#pragma unroll
    for (int d = 0; d < D; d += 4) {           // 8 independent fma chains
        oa0 = fmaf(__shfl(acca, d),     Uld[(d)     * D + lane], oa0);
        ob0 = fmaf(__shfl(accb, d),     Uld[(d)     * D + lane], ob0);
        oa1 = fmaf(__shfl(acca, d + 1), Uld[(d + 1) * D + lane], oa1);
        ob1 = fmaf(__shfl(accb, d + 1), Uld[(d + 1) * D + lane], ob1);
        oa2 = fmaf(__shfl(acca, d + 2), Uld[(d + 2) * D + lane], oa2);
        ob2 = fmaf(__shfl(accb, d + 2), Uld[(d + 2) * D + lane], ob2);
        oa3 = fmaf(__shfl(acca, d + 3), Uld[(d + 3) * D + lane], oa3);
        ob3 = fmaf(__shfl(accb, d + 3), Uld[(d + 3) * D + lane], ob3);
    }
    float outa = fmaxf(((oa0 + oa1) + (oa2 + oa3)) / (float)ca, 0.f);
    float outb = fmaxf(((ob0 + ob1) + (ob2 + ob3)) / (float)cb, 0.f);
    hout[(size_t)r0 * D + lane] = outa;
    hout[(size_t)r1 * D + lane] = outb;
    if (pg != nullptr) {
        part[wid][lane] = outa + outb;
        __syncthreads();
        if (wid == 0)
            pg[(size_t)bid * D + lane] =
                part[0][lane] + part[1][lane] + part[2][lane] + part[3][lane];
    }
}

// ---- head: 1 block x 512; wave w = batch w reduces its 256 pg partials ----
__global__ __launch_bounds__(512) void kHead(const float* __restrict__ pg,
        const float* __restrict__ Q, const float* __restrict__ P,
        float* __restrict__ out) {
    int wid = threadIdx.x >> 6, lane = threadIdx.x & 63;
    float md = 0.f;
#pragma unroll 8
    for (int k = 0; k < 256; ++k) md += pg[(size_t)(wid * 256 + k) * D + lane];
    md *= (1.0f / N);                           // m[b][lane]
    float t = 0.f;
#pragma unroll 8
    for (int k = 0; k < D; ++k) t = fmaf(Q[lane * D + k], __shfl(md, k), t);
    t = fmaxf(t, 0.f);
    float v = t * P[lane];
    for (int off = 32; off; off >>= 1) v += __shfl_down(v, off);
    if (lane == 0) out[wid] = v;
}

extern "C" void kernel_launch(void* const* d_in, const int* in_sizes, int n_in,
                              void* d_out, int out_size, void* d_ws, size_t ws_size,
                              hipStream_t stream) {
    const float* x   = (const float*)d_in[0];
    const float* adj = (const float*)d_in[1];
    const float* U0  = (const float*)d_in[2];
    const float* b0  = (const float*)d_in[3];
    const float* Us  = (const float*)d_in[4];
    const float* Q   = (const float*)d_in[5];
    const float* P   = (const float*)d_in[6];
    float* out = (float*)d_out;

    char* ws = (char*)d_ws;
    size_t off = 0;
    float* h0 = (float*)(ws + off); off += (size_t)BN * D * sizeof(float);  // 4 MB
    float* h1 = (float*)(ws + off); off += (size_t)BN * D * sizeof(float);  // 4 MB
    unsigned short* cols = (unsigned short*)(ws + off);
    off += (size_t)CAP * BN * sizeof(unsigned short);                       // 2 MB
    int* cnt = (int*)(ws + off); off += (size_t)BN * sizeof(int);           // 64 KB
    float* pg = (float*)(ws + off); off += (size_t)2048 * D * sizeof(float); // 512 KB

    kSLP<<<512, 256, 0, stream>>>(adj, x, U0, b0, cols, cnt, h0);
    kL<<<2048, 256, 0, stream>>>(h0, cols, cnt, Us + 0 * D * D, h1, nullptr);
    kL<<<2048, 256, 0, stream>>>(h1, cols, cnt, Us + 1 * D * D, h0, nullptr);
    kL<<<2048, 256, 0, stream>>>(h0, cols, cnt, Us + 2 * D * D, h1, pg);
    kHead<<<1, 512, 0, stream>>>(pg, Q, P, out);
}